// Round 6
// baseline (2074.897 us; speedup 1.0000x reference)
//
#include <hip/hip_runtime.h>
#include <hip/hip_bf16.h>
#include <hip/hip_fp16.h>

#define N_NODES   100000
#define N_FEAT    512
#define HIDDEN    64
#define N_CLASSES 40
#define KITER     10
#define ALPHA     0.1f
#define HPITCH    72
// chunked u layout: 3 chunks of 16 classes (chunk 2 = classes 32-39 + 8 pad),
// row pitch 16 halves (32 B) -> 3.2 MB per chunk, fits per-XCD L2 (4 MB)
#define CSTRIDE   ((size_t)N_NODES * 16)

typedef __attribute__((ext_vector_type(8))) short bf16x8;
typedef __attribute__((ext_vector_type(4))) float f32x4;

__device__ __forceinline__ float bf2f(unsigned short u) {
    union { unsigned int i; float f; } c;
    c.i = ((unsigned int)u) << 16;
    return c.f;
}
__device__ __forceinline__ unsigned short f2bf(float f) {
    union { float f; unsigned int u; } c; c.f = f;
    unsigned int r = c.u + 0x7FFFu + ((c.u >> 16) & 1u);   // RNE
    return (unsigned short)(r >> 16);
}

// ---------------- dtype detection (runs every call; data-driven, deterministic) ----
__global__ void zero_flags_kernel(int* __restrict__ flags) {
    if (threadIdx.x < 2) flags[threadIdx.x] = 0;
}

__global__ void detect_float_kernel(const unsigned short* __restrict__ w1raw,
                                    int* __restrict__ flags) {
    int i = blockIdx.x * blockDim.x + threadIdx.x;
    if (i < 32768) {
        unsigned short u = w1raw[i];
        if ((u & 0x7F80u) == 0x7F80u) atomicAdd(&flags[0], 1);
    }
}

__global__ void detect_edge_kernel(const int* __restrict__ ei, int* __restrict__ flags) {
    int i = blockIdx.x * blockDim.x + threadIdx.x;
    if (i < 2048) {
        if (ei[2 * i + 1] != 0) atomicAdd(&flags[1], 1);
    }
}

__device__ __forceinline__ int edge_row(const int* ei, int e, int E, int i64f) {
    return i64f ? ei[2 * e] : ei[e];
}
__device__ __forceinline__ int edge_col(const int* ei, int e, int E, int i64f) {
    return i64f ? ei[2 * E + 2 * e] : ei[E + e];
}

// ---------------- pack W1 into MFMA B-fragment order (bf16) ----------------
__global__ void pack_w1_kernel(const void* __restrict__ W1p, const int* __restrict__ flags,
                               unsigned short* __restrict__ pb) {
    int idx = blockIdx.x * 256 + threadIdx.x;   // 32768 total
    int j    = idx & 7;
    int lane = (idx >> 3) & 63;
    int ktnt = idx >> 9;            // nt*16 + kt
    int kt = ktnt & 15, nt = ktnt >> 4;
    int k = kt * 32 + (lane >> 4) * 8 + j;
    int n = nt * 16 + (lane & 15);
    unsigned short v;
    if (flags[0] > 0) v = f2bf(((const float*)W1p)[k * HIDDEN + n]);
    else              v = ((const unsigned short*)W1p)[k * HIDDEN + n];
    pb[idx] = v;
}

// ---------------- pack W2 (64x40) into B-frag order, N padded to 48 -------------
__global__ void pack_w2_kernel(const void* __restrict__ W2p, const int* __restrict__ flags,
                               unsigned short* __restrict__ pb2) {
    int idx = blockIdx.x * 256 + threadIdx.x;   // 3072 total
    if (idx >= 3072) return;
    int j    = idx & 7;
    int lane = (idx >> 3) & 63;
    int ktnt = idx >> 9;            // nt*2 + kt
    int kt = ktnt & 1, nt = ktnt >> 1;
    int k = kt * 32 + (lane >> 4) * 8 + j;
    int n = nt * 16 + (lane & 15);
    unsigned short v = 0;
    if (n < N_CLASSES) {
        if (flags[0] > 0) v = f2bf(((const float*)W2p)[k * N_CLASSES + n]);
        else              v = ((const unsigned short*)W2p)[k * N_CLASSES + n];
    }
    pb2[idx] = v;
}

// ---------------- MLP: h0 = relu(x@W1+b1)@W2+b2, both layers MFMA --------------
__global__ __launch_bounds__(256) void mlp_kernel(
    const void* __restrict__ xp,
    const unsigned short* __restrict__ pb,    // packed W1 B-frags
    const unsigned short* __restrict__ pb2,   // packed W2 B-frags
    const void* __restrict__ b1p,
    const void* __restrict__ b2p,
    const int* __restrict__ flags,
    const float* __restrict__ dinv,
    float* __restrict__ h0,
    __half* __restrict__ u0)
{
    __shared__ unsigned short hsb[16 * HPITCH];   // h in bf16, 2.25 KB
    const int t    = threadIdx.x;
    const int wave = t >> 6;
    const int lane = t & 63;
    const int quad = lane >> 4;
    const int ml   = lane & 15;
    const int base = blockIdx.x * 16;
    const int isf32 = flags[0] > 0;

    const bf16x8* pbv = (const bf16x8*)pb;

    // ---- layer 1: MFMA 16x16x32, m=16 nodes, n-tile=wave ----
    f32x4 acc = {0.f, 0.f, 0.f, 0.f};
    if (!isf32) {
        const unsigned short* xrow = (const unsigned short*)xp
                                   + (size_t)(base + ml) * N_FEAT + quad * 8;
        #pragma unroll
        for (int kt = 0; kt < 16; ++kt) {
            bf16x8 a = *(const bf16x8*)(xrow + kt * 32);
            bf16x8 b = pbv[(wave * 16 + kt) * 64 + lane];
            acc = __builtin_amdgcn_mfma_f32_16x16x32_bf16(a, b, acc, 0, 0, 0);
        }
    } else {
        const float* xf = (const float*)xp + (size_t)(base + ml) * N_FEAT + quad * 8;
        #pragma unroll
        for (int kt = 0; kt < 16; ++kt) {
            float4 lo = *(const float4*)(xf + kt * 32);
            float4 hi = *(const float4*)(xf + kt * 32 + 4);
            bf16x8 a;
            a[0] = (short)f2bf(lo.x); a[1] = (short)f2bf(lo.y);
            a[2] = (short)f2bf(lo.z); a[3] = (short)f2bf(lo.w);
            a[4] = (short)f2bf(hi.x); a[5] = (short)f2bf(hi.y);
            a[6] = (short)f2bf(hi.z); a[7] = (short)f2bf(hi.w);
            bf16x8 b = pbv[(wave * 16 + kt) * 64 + lane];
            acc = __builtin_amdgcn_mfma_f32_16x16x32_bf16(a, b, acc, 0, 0, 0);
        }
    }

    float b1v = isf32 ? ((const float*)b1p)[wave * 16 + ml]
                      : bf2f(((const unsigned short*)b1p)[wave * 16 + ml]);
    #pragma unroll
    for (int r = 0; r < 4; ++r)
        hsb[(quad * 4 + r) * HPITCH + wave * 16 + ml] = f2bf(fmaxf(acc[r] + b1v, 0.0f));
    __syncthreads();

    // ---- layer 2: MFMA, m=16 nodes, K=64, n padded to 48 (3 tiles) ----
    if (wave < 3) {
        const bf16x8* pb2v = (const bf16x8*)pb2;
        f32x4 acc2 = {0.f, 0.f, 0.f, 0.f};
        #pragma unroll
        for (int kt = 0; kt < 2; ++kt) {
            bf16x8 a = *(const bf16x8*)(hsb + ml * HPITCH + kt * 32 + quad * 8);
            bf16x8 b = pb2v[(wave * 2 + kt) * 64 + lane];
            acc2 = __builtin_amdgcn_mfma_f32_16x16x32_bf16(a, b, acc2, 0, 0, 0);
        }
        int n = wave * 16 + ml;
        if (n < N_CLASSES) {
            float b2v = isf32 ? ((const float*)b2p)[n] : bf2f(((const unsigned short*)b2p)[n]);
            int cchunk = n >> 4, jj = n & 15;
            #pragma unroll
            for (int r = 0; r < 4; ++r) {
                int node = base + quad * 4 + r;
                float v = acc2[r] + b2v;
                h0[(size_t)node * N_CLASSES + n] = v;
                u0[(size_t)cchunk * CSTRIDE + ((size_t)node << 4) + jj]
                    = __float2half(dinv[node] * v);
            }
        }
    }
}

// ---------------- graph preprocessing ----------------
__global__ void zero_cnt_kernel(int* __restrict__ cnt) {
    int i = blockIdx.x * blockDim.x + threadIdx.x;
    if (i < N_NODES) cnt[i] = 0;
}

__global__ void count_kernel(const int* __restrict__ ei, const int* __restrict__ flags,
                             int* __restrict__ cnt, int E) {
    int e = blockIdx.x * blockDim.x + threadIdx.x;
    int i64f = flags[1] == 0;
    if (e < E) atomicAdd(&cnt[edge_col(ei, e, E, i64f)], 1);
}

__global__ void dinv_kernel(const int* __restrict__ cnt, float* __restrict__ dinv) {
    int i = blockIdx.x * blockDim.x + threadIdx.x;
    if (i < N_NODES) dinv[i] = rsqrtf((float)cnt[i] + 1.0f);  // +1 self-loop
}

// shuffle-based exclusive scan: 4096 elems/tile, 4 barriers/tile, 25 tiles
__global__ __launch_bounds__(1024) void scan_kernel(
    const int* __restrict__ cnt, int* __restrict__ rptr, int* __restrict__ wpos, int E)
{
    __shared__ int wsum[16];
    __shared__ int carry_s, tiletot_s;
    const int t = threadIdx.x, wave = t >> 6, lane = t & 63;
    if (t == 0) carry_s = 0;
    __syncthreads();
    for (int base = 0; base < N_NODES; base += 4096) {
        int i0 = base + t * 4;
        int v0 = (i0 + 0 < N_NODES) ? cnt[i0 + 0] : 0;
        int v1 = (i0 + 1 < N_NODES) ? cnt[i0 + 1] : 0;
        int v2 = (i0 + 2 < N_NODES) ? cnt[i0 + 2] : 0;
        int v3 = (i0 + 3 < N_NODES) ? cnt[i0 + 3] : 0;
        int tl = v0 + v1 + v2 + v3;
        int sc = tl;
        #pragma unroll
        for (int off = 1; off < 64; off <<= 1) {
            int u = __shfl_up(sc, off, 64);
            if (lane >= off) sc += u;
        }
        if (lane == 63) wsum[wave] = sc;
        int wexcl = sc - tl;
        __syncthreads();
        if (wave == 0) {
            int wv = (lane < 16) ? wsum[lane] : 0;
            int ws = wv;
            #pragma unroll
            for (int off = 1; off < 16; off <<= 1) {
                int u = __shfl_up(ws, off, 64);
                if (lane >= off) ws += u;
            }
            if (lane < 16) wsum[lane] = ws - wv;   // exclusive
            if (lane == 15) tiletot_s = ws;        // inclusive tile total
        }
        __syncthreads();
        int P  = carry_s + wsum[wave] + wexcl;
        int e0 = P, e1 = P + v0, e2 = e1 + v1, e3 = e2 + v2;
        if (i0 + 0 < N_NODES) { rptr[i0 + 0] = e0; wpos[i0 + 0] = e0; }
        if (i0 + 1 < N_NODES) { rptr[i0 + 1] = e1; wpos[i0 + 1] = e1; }
        if (i0 + 2 < N_NODES) { rptr[i0 + 2] = e2; wpos[i0 + 2] = e2; }
        if (i0 + 3 < N_NODES) { rptr[i0 + 3] = e3; wpos[i0 + 3] = e3; }
        __syncthreads();
        if (t == 0) carry_s += tiletot_s;
        __syncthreads();
    }
    if (t == 0) rptr[N_NODES] = E;
}

// fill: only the source id; norm is folded into u = dinv*z
__global__ void fill_kernel(const int* __restrict__ ei, const int* __restrict__ flags,
                            int* __restrict__ wpos, int* __restrict__ srow, int E)
{
    int e = blockIdx.x * blockDim.x + threadIdx.x;
    int i64f = flags[1] == 0;
    if (e < E) {
        int r = edge_row(ei, e, E, i64f);
        int c = edge_col(ei, e, E, i64f);
        int pos = atomicAdd(&wpos[c], 1);
        __builtin_nontemporal_store(r, &srow[pos]);
    }
}

// ---------------- propagation pass over one class-chunk --------------------------
// u = dinv*z stored fp16, chunk rows of 16 halves (32 B). 16 nodes/wave, 4 lanes/node.
// z_out = a*h0 + (1-a)*dinv_c*(sum_r u[r] + u[c]);  u_out = dinv_c*z_out
__global__ __launch_bounds__(256) void prop_kernel(
    const __half* __restrict__ uin, const float* __restrict__ h0,
    const float* __restrict__ dinv, const int* __restrict__ rptr,
    const int* __restrict__ srow, __half* __restrict__ uout, int chunk)
{
    const int t = threadIdx.x;
    const int wave = t >> 6;
    const int lane = t & 63;
    const int g = lane >> 2, q = lane & 3;
    const int node = blockIdx.x * 64 + wave * 16 + g;
    const bool nv = node < N_NODES;
    const int cls0 = chunk * 16 + (q << 2);
    const bool cvalid = cls0 < N_CLASSES;

    const __half* ub = uin + (size_t)chunk * CSTRIDE;
    int beg = 0, end = 0;
    float di = 0.f;
    if (nv) { beg = rptr[node]; end = rptr[node + 1]; di = dinv[node]; }

    uint2 su = make_uint2(0u, 0u);
    if (nv && cvalid) su = *(const uint2*)(ub + ((size_t)node << 4) + (q << 2));
    float4 h0v = make_float4(0.f, 0.f, 0.f, 0.f);
    if (nv && cvalid) h0v = *(const float4*)(h0 + (size_t)node * N_CLASSES + cls0);

    int m = (end - beg + 3) >> 2;
    m = max(m, __shfl_xor(m, 4, 64));
    m = max(m, __shfl_xor(m, 8, 64));
    m = max(m, __shfl_xor(m, 16, 64));
    m = max(m, __shfl_xor(m, 32, 64));

    float a0 = 0.f, a1 = 0.f, a2 = 0.f, a3 = 0.f;
    for (int ch = 0; ch < m; ++ch) {
        int idx = beg + (ch << 2) + q;
        int r = 0;
        if (idx < end) r = __builtin_nontemporal_load(srow + idx);
        #pragma unroll
        for (int j = 0; j < 4; ++j) {
            int rj = __shfl(r, (g << 2) + j, 64);
            if (cvalid && (beg + (ch << 2) + j < end)) {
                uint2 zz = *(const uint2*)(ub + ((size_t)rj << 4) + (q << 2));
                __half2* ph = (__half2*)&zz;
                float2 f0 = __half22float2(ph[0]);
                float2 f1 = __half22float2(ph[1]);
                a0 += f0.x; a1 += f0.y; a2 += f1.x; a3 += f1.y;
            }
        }
    }

    if (nv && cvalid) {
        __half2* ps = (__half2*)&su;
        float2 s0 = __half22float2(ps[0]);
        float2 s1 = __half22float2(ps[1]);
        float o0 = ALPHA * h0v.x + (1.0f - ALPHA) * di * (a0 + s0.x);
        float o1 = ALPHA * h0v.y + (1.0f - ALPHA) * di * (a1 + s0.y);
        float o2 = ALPHA * h0v.z + (1.0f - ALPHA) * di * (a2 + s1.x);
        float o3 = ALPHA * h0v.w + (1.0f - ALPHA) * di * (a3 + s1.y);
        __half2 q01 = __floats2half2_rn(di * o0, di * o1);
        __half2 q23 = __floats2half2_rn(di * o2, di * o3);
        unsigned int lo = *(unsigned int*)&q01;
        unsigned int hi = *(unsigned int*)&q23;
        unsigned long long pk = ((unsigned long long)hi << 32) | (unsigned long long)lo;
        __builtin_nontemporal_store(pk,
            (unsigned long long*)(uout + (size_t)chunk * CSTRIDE + ((size_t)node << 4) + (q << 2)));
    }
}

// ---------------- log_softmax + store (fp32 or bf16 per flags[0]) ----------------
__global__ __launch_bounds__(256) void lsm_kernel(
    const __half* __restrict__ u, const float* __restrict__ dinv,
    const int* __restrict__ flags, void* __restrict__ outp)
{
    const int wave = threadIdx.x >> 6;
    const int lane = threadIdx.x & 63;
    const int node = blockIdx.x * 4 + wave;
    const int isf32 = flags[0] > 0;

    float di = dinv[node];
    float v = -1e30f;
    if (lane < N_CLASSES) {
        int cchunk = lane >> 4, j = lane & 15;
        __half uu = u[(size_t)cchunk * CSTRIDE + ((size_t)node << 4) + j];
        v = __half2float(uu) / di;
    }
    float mx = v;
    #pragma unroll
    for (int o = 32; o; o >>= 1) mx = fmaxf(mx, __shfl_xor(mx, o, 64));
    float e = (lane < N_CLASSES) ? expf(v - mx) : 0.0f;
    float s = e;
    #pragma unroll
    for (int o = 32; o; o >>= 1) s += __shfl_xor(s, o, 64);
    float ls = logf(s);
    if (lane < N_CLASSES) {
        float r = v - mx - ls;
        size_t idx = (size_t)node * N_CLASSES + lane;
        if (isf32) ((float*)outp)[idx] = r;
        else       ((__hip_bfloat16*)outp)[idx] = __float2bfloat16(r);
    }
}

extern "C" void kernel_launch(void* const* d_in, const int* in_sizes, int n_in,
                              void* d_out, int out_size, void* d_ws, size_t ws_size,
                              hipStream_t stream)
{
    const void* x  = d_in[0];
    const void* W1 = d_in[1];
    const void* b1 = d_in[2];
    const void* W2 = d_in[3];
    const void* b2 = d_in[4];
    const int* ei = (const int*)d_in[5];
    const int E = in_sizes[5] / 2;

    // workspace carve-up (256B aligned)
    char* ws = (char*)d_ws;
    size_t off = 0;
    auto carve = [&](size_t bytes) -> void* {
        void* p = ws + off;
        off = (off + bytes + 255) & ~(size_t)255;
        return p;
    };
    float*  h0    = (float*) carve((size_t)N_NODES * N_CLASSES * 4);
    __half* uA    = (__half*)carve(3 * CSTRIDE * 2);
    __half* uB    = (__half*)carve(3 * CSTRIDE * 2);
    int*    cnt   = (int*)   carve((size_t)N_NODES * 4);
    float*  dinv  = (float*) carve((size_t)N_NODES * 4);
    int*    rptr  = (int*)   carve((size_t)(N_NODES + 1) * 4);
    int*    wpos  = (int*)   carve((size_t)N_NODES * 4);
    int*    srow  = (int*)   carve((size_t)E * 4);
    unsigned short* pb  = (unsigned short*)carve(32768 * 2);
    unsigned short* pb2 = (unsigned short*)carve(3072 * 2);
    int*    flags = (int*)   carve(2 * sizeof(int));
    (void)ws_size; (void)n_in; (void)out_size;

    const int mlpBlocks  = N_NODES / 16;             // 6250
    const int propBlocks = (N_NODES + 63) / 64;      // 1563
    const int nThreads1  = (N_NODES + 255) / 256;
    const int eBlocks    = (E + 255) / 256;

    // dtype detection + weight packing
    zero_flags_kernel<<<1, 64, 0, stream>>>(flags);
    detect_float_kernel<<<128, 256, 0, stream>>>((const unsigned short*)W1, flags);
    detect_edge_kernel<<<8, 256, 0, stream>>>(ei, flags);
    pack_w1_kernel<<<128, 256, 0, stream>>>(W1, flags, pb);
    pack_w2_kernel<<<12, 256, 0, stream>>>(W2, flags, pb2);

    // CSR-by-destination build (dinv needed by mlp, so degrees first)
    zero_cnt_kernel<<<nThreads1, 256, 0, stream>>>(cnt);
    count_kernel<<<eBlocks, 256, 0, stream>>>(ei, flags, cnt, E);
    dinv_kernel<<<nThreads1, 256, 0, stream>>>(cnt, dinv);
    scan_kernel<<<1, 1024, 0, stream>>>(cnt, rptr, wpos, E);
    fill_kernel<<<eBlocks, 256, 0, stream>>>(ei, flags, wpos, srow, E);

    // MLP (both layers MFMA); writes h0 fp32 + u0 = dinv*h0 chunked fp16
    mlp_kernel<<<mlpBlocks, 256, 0, stream>>>(x, pb, pb2, b1, b2, flags, dinv, h0, uA);

    // K propagation steps, 3 class-chunk passes each (ping-pong u buffers)
    const __half* zin = uA;
    __half* zout = uB;
    const __half* zlast = uA;
    for (int it = 0; it < KITER; ++it) {
        for (int c = 0; c < 3; ++c)
            prop_kernel<<<propBlocks, 256, 0, stream>>>(zin, h0, dinv, rptr, srow, zout, c);
        zlast = zout;
        zin = zout;
        zout = (zout == uB) ? uA : uB;
    }

    lsm_kernel<<<N_NODES / 4, 256, 0, stream>>>(zlast, dinv, flags, d_out);
}